// Round 8
// baseline (324.377 us; speedup 1.0000x reference)
//
#include <hip/hip_runtime.h>
#include <cstddef>

constexpr int Bc = 2, Sc = 2048, Hc = 16, Dc = 64, HIDc = 1024;
#define NEG_INF -10000.0f

typedef _Float16 half8  __attribute__((ext_vector_type(8)));  // K=32 MFMA A/B frag
typedef _Float16 half4  __attribute__((ext_vector_type(4)));  // K=16 MFMA A/B frag
typedef float   floatx4 __attribute__((ext_vector_type(4)));  // MFMA C/D frag

// ---------------------------------------------------------------------------
// cvt_x: x fp32 [4096][1024] -> f16 same layout. 8 elements/thread.
// ---------------------------------------------------------------------------
__global__ __launch_bounds__(256) void cvt_x_kernel(const float* __restrict__ x,
                                                    _Float16* __restrict__ xh) {
    int i = (blockIdx.x * 256 + threadIdx.x) * 8;
    float4 a = *(const float4*)(x + i);
    float4 b = *(const float4*)(x + i + 4);
    half8 h;
    h[0] = (_Float16)a.x; h[1] = (_Float16)a.y; h[2] = (_Float16)a.z; h[3] = (_Float16)a.w;
    h[4] = (_Float16)b.x; h[5] = (_Float16)b.y; h[6] = (_Float16)b.z; h[7] = (_Float16)b.w;
    *(half8*)(xh + i) = h;
}

// ---------------------------------------------------------------------------
// cvt_w: W fp32 [k][n] -> Wt f16 [n][k] (transposed), per z in {q,k,v}.
// ---------------------------------------------------------------------------
__global__ __launch_bounds__(256) void cvt_w_kernel(const float* __restrict__ Wq,
                                                    const float* __restrict__ Wk,
                                                    const float* __restrict__ Wv,
                                                    _Float16* __restrict__ Wt) {
    const float* W = (blockIdx.z == 0) ? Wq : (blockIdx.z == 1) ? Wk : Wv;
    _Float16* out = Wt + (size_t)blockIdx.z * HIDc * HIDc;
    __shared__ _Float16 T[64][65];
    const int t = threadIdx.x;
    const int kb = blockIdx.x * 64, nb = blockIdx.y * 64;
    const int r = t >> 2, c4 = (t & 3) * 16;
    #pragma unroll
    for (int i = 0; i < 16; i += 4) {
        float4 a = *(const float4*)(W + (size_t)(kb + r) * HIDc + nb + c4 + i);
        T[c4 + i + 0][r] = (_Float16)a.x;
        T[c4 + i + 1][r] = (_Float16)a.y;
        T[c4 + i + 2][r] = (_Float16)a.z;
        T[c4 + i + 3][r] = (_Float16)a.w;
    }
    __syncthreads();
    const int n = t >> 2, k4 = (t & 3) * 16;
    half8 o0, o1;
    #pragma unroll
    for (int j = 0; j < 8; ++j) { o0[j] = T[n][k4 + j]; o1[j] = T[n][k4 + 8 + j]; }
    *(half8*)(out + (size_t)(nb + n) * HIDc + kb + k4)     = o0;
    *(half8*)(out + (size_t)(nb + n) * HIDc + kb + k4 + 8) = o1;
}

// ---------------------------------------------------------------------------
// proj: unchanged from R5-R7 (passing). C = x@W + bias via f16 MFMA, 128x128
// tile, BK=32, 4 waves x (64x64), full half-row staging (2x uint4).
// ---------------------------------------------------------------------------
#define PSTR 40
__global__ __launch_bounds__(256) void proj_kernel(
    const _Float16* __restrict__ xh, const _Float16* __restrict__ Wt,
    const float* __restrict__ bq, const float* __restrict__ bk, const float* __restrict__ bv,
    _Float16* __restrict__ qw, _Float16* __restrict__ kw, _Float16* __restrict__ vt)
{
    const int z = blockIdx.z;
    const _Float16* Wz = Wt + (size_t)z * HIDc * HIDc;
    const float* bias = (z == 0) ? bq : (z == 1) ? bk : bv;

    __shared__ _Float16 As[128 * PSTR];
    __shared__ _Float16 Bs[128 * PSTR];

    const int t = threadIdx.x;
    const int lane = t & 63, w = t >> 6;
    const int quad = lane >> 4, l16 = lane & 15;
    const int m0 = blockIdx.y * 128, n0 = blockIdx.x * 128;
    const int wm = (w >> 1) * 64, wn = (w & 1) * 64;
    const int sr = t >> 1, sh = (t & 1) * 16;

    floatx4 acc[4][4];
    #pragma unroll
    for (int mb = 0; mb < 4; ++mb)
        #pragma unroll
        for (int nb = 0; nb < 4; ++nb) acc[mb][nb] = floatx4{0.f, 0.f, 0.f, 0.f};

    for (int k0 = 0; k0 < HIDc; k0 += 32) {
        const _Float16* ap = xh + (size_t)(m0 + sr) * HIDc + k0 + sh;
        const _Float16* bp = Wz + (size_t)(n0 + sr) * HIDc + k0 + sh;
        uint4 a0 = *(const uint4*)(ap);
        uint4 a1 = *(const uint4*)(ap + 8);
        uint4 b0 = *(const uint4*)(bp);
        uint4 b1 = *(const uint4*)(bp + 8);
        __syncthreads();
        *(uint4*)(As + sr * PSTR + sh)     = a0;
        *(uint4*)(As + sr * PSTR + sh + 8) = a1;
        *(uint4*)(Bs + sr * PSTR + sh)     = b0;
        *(uint4*)(Bs + sr * PSTR + sh + 8) = b1;
        __syncthreads();

        half8 af[4], bf[4];
        #pragma unroll
        for (int mb = 0; mb < 4; ++mb)
            af[mb] = *(const half8*)(As + (wm + mb * 16 + l16) * PSTR + quad * 8);
        #pragma unroll
        for (int nb = 0; nb < 4; ++nb)
            bf[nb] = *(const half8*)(Bs + (wn + nb * 16 + l16) * PSTR + quad * 8);
        #pragma unroll
        for (int mb = 0; mb < 4; ++mb)
            #pragma unroll
            for (int nb = 0; nb < 4; ++nb)
                acc[mb][nb] = __builtin_amdgcn_mfma_f32_16x16x32_f16(
                    af[mb], bf[nb], acc[mb][nb], 0, 0, 0);
    }

    #pragma unroll
    for (int nb = 0; nb < 4; ++nb) {
        const int N = n0 + wn + nb * 16 + l16;
        const float bi = bias[N];
        const int h = N >> 6, d = N & 63;
        #pragma unroll
        for (int mb = 0; mb < 4; ++mb) {
            #pragma unroll
            for (int r = 0; r < 4; ++r) {
                const int M = m0 + wm + mb * 16 + quad * 4 + r;
                const int bI = M >> 11, s = M & (Sc - 1);
                const float v = acc[mb][nb][r] + bi;
                if (z == 0)
                    qw[(((size_t)(bI * Hc + h)) * Sc + s) * Dc + d] = (_Float16)(v * 0.125f);
                else if (z == 1)
                    kw[(((size_t)(bI * Hc + h)) * Sc + s) * Dc + d] = (_Float16)v;
                else
                    vt[(((size_t)(bI * Hc + h)) * Dc + d) * Sc + s] = (_Float16)v;
            }
        }
    }
}

// ---------------------------------------------------------------------------
// attn R8: R7's zero-shuffle transposed-scores structure + FULL double
// prefetch. R7 exposed V-load latency (all pipes <15%); now BOTH K and V for
// tile kt+1 are issued at the top of iteration kt and consumed one iteration
// later, so every global load has ~a full loop body to land. No barriers in
// the key loop. #pragma unroll 2 turns the register rotate into renaming.
// ---------------------------------------------------------------------------
__global__ __launch_bounds__(256, 2) void attn_kernel(
    const _Float16* __restrict__ qw, const _Float16* __restrict__ kw,
    const _Float16* __restrict__ vt, const int* __restrict__ mask,
    float* __restrict__ out)
{
    __shared__ float adder[Sc];               // 8 KB additive mask

    const int t = threadIdx.x;
    const int lane = t & 63, w = t >> 6;
    const int quad = lane >> 4, l16 = lane & 15;
    const int bh = blockIdx.y;
    const int bI = bh >> 4, h = bh & 15;

    const _Float16* Qp = qw + (size_t)bh * Sc * Dc;
    const _Float16* Kp = kw + (size_t)bh * Sc * Dc;
    const _Float16* Vp = vt + (size_t)bh * Dc * Sc;

    {   // mask -> additive adder in LDS (once per block)
        const int4* mp = (const int4*)(mask + bI * Sc);
        #pragma unroll
        for (int i = 0; i < 2; ++i) {
            int4 m4 = mp[t * 2 + i];
            int base = (t * 2 + i) * 4;
            adder[base + 0] = (1.0f - (float)m4.x) * NEG_INF;
            adder[base + 1] = (1.0f - (float)m4.y) * NEG_INF;
            adder[base + 2] = (1.0f - (float)m4.z) * NEG_INF;
            adder[base + 3] = (1.0f - (float)m4.w) * NEG_INF;
        }
    }
    __syncthreads();   // adder ready (only barrier in the kernel)

    const int qrow = blockIdx.x * 128 + w * 32;
    // Q as B-frag for S^T: B[n=q=l16][k=d=quad*8+j]
    half8 aq[2][2];
    #pragma unroll
    for (int s = 0; s < 2; ++s)
        #pragma unroll
        for (int hh = 0; hh < 2; ++hh)
            aq[s][hh] = *(const half8*)(Qp + (size_t)(qrow + 16 * s + l16) * Dc
                                        + hh * 32 + quad * 8);

    floatx4 o[2][4];           // [q-set][d-tile]; D[m=q=quad*4+r][n=d=l16]
    #pragma unroll
    for (int s = 0; s < 2; ++s)
        #pragma unroll
        for (int db = 0; db < 4; ++db) o[s][db] = floatx4{0.f, 0.f, 0.f, 0.f};
    float lsum[2] = {0.f, 0.f};   // per-lane denom partial for q = l16

    // preload tile 0: K as A-frag A[m=key=l16][k=d=quad*8+j];
    //                 V as B-frag B[n=d=l16][k=key=quad*4+i]
    half8 kb[4][2];
    half4 vb[4][4];
    #pragma unroll
    for (int nb = 0; nb < 4; ++nb) {
        #pragma unroll
        for (int hh = 0; hh < 2; ++hh)
            kb[nb][hh] = *(const half8*)(Kp + (size_t)(nb * 16 + l16) * Dc
                                         + hh * 32 + quad * 8);
        #pragma unroll
        for (int db = 0; db < 4; ++db)
            vb[nb][db] = *(const half4*)(Vp + (size_t)(db * 16 + l16) * Sc
                                         + nb * 16 + quad * 4);
    }

    #pragma unroll 2
    for (int kt = 0; kt < Sc; kt += 64) {
        // ---- prefetch next tile's K and V (consumed next iteration)
        const int ktn = (kt + 64 < Sc) ? kt + 64 : 0;
        half8 kbn[4][2];
        half4 vbn[4][4];
        #pragma unroll
        for (int nb = 0; nb < 4; ++nb) {
            #pragma unroll
            for (int hh = 0; hh < 2; ++hh)
                kbn[nb][hh] = *(const half8*)(Kp + (size_t)(ktn + nb * 16 + l16) * Dc
                                              + hh * 32 + quad * 8);
            #pragma unroll
            for (int db = 0; db < 4; ++db)
                vbn[nb][db] = *(const half4*)(Vp + (size_t)(db * 16 + l16) * Sc
                                              + ktn + nb * 16 + quad * 4);
        }

        // ---- S^T = K @ Q^T : D[m=key][n=q]  (kb in registers)
        floatx4 st[2][4];
        #pragma unroll
        for (int s = 0; s < 2; ++s)
            #pragma unroll
            for (int nb = 0; nb < 4; ++nb) {
                floatx4 acc = floatx4{0.f, 0.f, 0.f, 0.f};
                acc = __builtin_amdgcn_mfma_f32_16x16x32_f16(kb[nb][0], aq[s][0], acc, 0, 0, 0);
                acc = __builtin_amdgcn_mfma_f32_16x16x32_f16(kb[nb][1], aq[s][1], acc, 0, 0, 0);
                st[s][nb] = acc;
            }

        // ---- P = exp(S^T + mask): registers stay in place as PV A-frags
        half4 pa[2][4];
        #pragma unroll
        for (int nb = 0; nb < 4; ++nb) {
            const float4 a4 = *(const float4*)&adder[kt + nb * 16 + quad * 4];
            const float ad[4] = {a4.x, a4.y, a4.z, a4.w};
            #pragma unroll
            for (int s = 0; s < 2; ++s)
                #pragma unroll
                for (int r = 0; r < 4; ++r) {
                    const float p = __expf(st[s][nb][r] + ad[r]);
                    lsum[s] += p;
                    pa[s][nb][r] = (_Float16)p;
                }
        }

        // ---- O += P @ V (K=16 MFMA; pa is already the A-frag; vb in regs)
        #pragma unroll
        for (int s = 0; s < 2; ++s)
            #pragma unroll
            for (int nb = 0; nb < 4; ++nb)
                #pragma unroll
                for (int db = 0; db < 4; ++db)
                    o[s][db] = __builtin_amdgcn_mfma_f32_16x16x16f16(
                        pa[s][nb], vb[nb][db], o[s][db], 0, 0, 0);

        // ---- rotate prefetched K and V (renamed away under unroll 2)
        #pragma unroll
        for (int nb = 0; nb < 4; ++nb) {
            #pragma unroll
            for (int hh = 0; hh < 2; ++hh) kb[nb][hh] = kbn[nb][hh];
            #pragma unroll
            for (int db = 0; db < 4; ++db) vb[nb][db] = vbn[nb][db];
        }
    }

    // ---- epilogue: reduce denom over quads, redistribute, normalize, store
    #pragma unroll
    for (int s = 0; s < 2; ++s) {
        lsum[s] += __shfl_xor(lsum[s], 16, 64);
        lsum[s] += __shfl_xor(lsum[s], 32, 64);   // total for q=l16, all lanes
    }
    float* op = out + (size_t)bI * Sc * HIDc + h * Dc;
    #pragma unroll
    for (int s = 0; s < 2; ++s)
        #pragma unroll
        for (int r = 0; r < 4; ++r) {
            const float inv = 1.0f / __shfl(lsum[s], quad * 4 + r, 64);
            const int q = qrow + 16 * s + quad * 4 + r;
            #pragma unroll
            for (int db = 0; db < 4; ++db)
                op[(size_t)q * HIDc + db * 16 + l16] = o[s][db][r] * inv;
        }
}

// ---------------------------------------------------------------------------
extern "C" void kernel_launch(void* const* d_in, const int* in_sizes, int n_in,
                              void* d_out, int out_size, void* d_ws, size_t ws_size,
                              hipStream_t stream) {
    const float* x    = (const float*)d_in[0];
    const int*   mask = (const int*)  d_in[1];
    const float* Wq   = (const float*)d_in[2];
    const float* bq   = (const float*)d_in[3];
    const float* Wk   = (const float*)d_in[4];
    const float* bk   = (const float*)d_in[5];
    const float* Wv   = (const float*)d_in[6];
    const float* bv   = (const float*)d_in[7];
    float* out = (float*)d_out;

    // workspace (f16): xh 8MB | Wt 6MB | qw 8MB | kw 8MB | vt 8MB = 38MB
    char* ws = (char*)d_ws;
    _Float16* xh = (_Float16*)(ws);
    _Float16* Wt = (_Float16*)(ws + (size_t)8  * 1024 * 1024);
    _Float16* qw = (_Float16*)(ws + (size_t)14 * 1024 * 1024);
    _Float16* kw = (_Float16*)(ws + (size_t)22 * 1024 * 1024);
    _Float16* vt = (_Float16*)(ws + (size_t)30 * 1024 * 1024);

    cvt_x_kernel<<<(Bc * Sc * HIDc) / (256 * 8), 256, 0, stream>>>(x, xh);
    cvt_w_kernel<<<dim3(HIDc / 64, HIDc / 64, 3), 256, 0, stream>>>(Wq, Wk, Wv, Wt);
    proj_kernel<<<dim3(HIDc / 128, (Bc * Sc) / 128, 3), 256, 0, stream>>>(
        xh, Wt, bq, bk, bv, qw, kw, vt);
    attn_kernel<<<dim3(Sc / 128, Bc * Hc), 256, 0, stream>>>(qw, kw, vt, mask, out);
}

// Round 9
// 201.227 us; speedup vs baseline: 1.6120x; 1.6120x over previous
//
#include <hip/hip_runtime.h>
#include <cstddef>

constexpr int Bc = 2, Sc = 2048, Hc = 16, Dc = 64, HIDc = 1024;
#define NEG_INF -10000.0f

typedef _Float16 half8  __attribute__((ext_vector_type(8)));  // K=32 MFMA A/B frag
typedef _Float16 half4  __attribute__((ext_vector_type(4)));  // K=16 MFMA A/B frag
typedef float   floatx4 __attribute__((ext_vector_type(4)));  // MFMA C/D frag

// ---------------------------------------------------------------------------
// cvt_x: x fp32 [4096][1024] -> f16 same layout. 8 elements/thread.
// ---------------------------------------------------------------------------
__global__ __launch_bounds__(256) void cvt_x_kernel(const float* __restrict__ x,
                                                    _Float16* __restrict__ xh) {
    int i = (blockIdx.x * 256 + threadIdx.x) * 8;
    float4 a = *(const float4*)(x + i);
    float4 b = *(const float4*)(x + i + 4);
    half8 h;
    h[0] = (_Float16)a.x; h[1] = (_Float16)a.y; h[2] = (_Float16)a.z; h[3] = (_Float16)a.w;
    h[4] = (_Float16)b.x; h[5] = (_Float16)b.y; h[6] = (_Float16)b.z; h[7] = (_Float16)b.w;
    *(half8*)(xh + i) = h;
}

// ---------------------------------------------------------------------------
// cvt_w: W fp32 [k][n] -> Wt f16 [n][k] (transposed), per z in {q,k,v}.
// ---------------------------------------------------------------------------
__global__ __launch_bounds__(256) void cvt_w_kernel(const float* __restrict__ Wq,
                                                    const float* __restrict__ Wk,
                                                    const float* __restrict__ Wv,
                                                    _Float16* __restrict__ Wt) {
    const float* W = (blockIdx.z == 0) ? Wq : (blockIdx.z == 1) ? Wk : Wv;
    _Float16* out = Wt + (size_t)blockIdx.z * HIDc * HIDc;
    __shared__ _Float16 T[64][65];
    const int t = threadIdx.x;
    const int kb = blockIdx.x * 64, nb = blockIdx.y * 64;
    const int r = t >> 2, c4 = (t & 3) * 16;
    #pragma unroll
    for (int i = 0; i < 16; i += 4) {
        float4 a = *(const float4*)(W + (size_t)(kb + r) * HIDc + nb + c4 + i);
        T[c4 + i + 0][r] = (_Float16)a.x;
        T[c4 + i + 1][r] = (_Float16)a.y;
        T[c4 + i + 2][r] = (_Float16)a.z;
        T[c4 + i + 3][r] = (_Float16)a.w;
    }
    __syncthreads();
    const int n = t >> 2, k4 = (t & 3) * 16;
    half8 o0, o1;
    #pragma unroll
    for (int j = 0; j < 8; ++j) { o0[j] = T[n][k4 + j]; o1[j] = T[n][k4 + 8 + j]; }
    *(half8*)(out + (size_t)(nb + n) * HIDc + kb + k4)     = o0;
    *(half8*)(out + (size_t)(nb + n) * HIDc + kb + k4 + 8) = o1;
}

// ---------------------------------------------------------------------------
// proj: unchanged from R5-R8 (passing). C = x@W + bias via f16 MFMA, 128x128
// tile, BK=32, 4 waves x (64x64), full half-row staging (2x uint4).
// ---------------------------------------------------------------------------
#define PSTR 40
__global__ __launch_bounds__(256) void proj_kernel(
    const _Float16* __restrict__ xh, const _Float16* __restrict__ Wt,
    const float* __restrict__ bq, const float* __restrict__ bk, const float* __restrict__ bv,
    _Float16* __restrict__ qw, _Float16* __restrict__ kw, _Float16* __restrict__ vt)
{
    const int z = blockIdx.z;
    const _Float16* Wz = Wt + (size_t)z * HIDc * HIDc;
    const float* bias = (z == 0) ? bq : (z == 1) ? bk : bv;

    __shared__ _Float16 As[128 * PSTR];
    __shared__ _Float16 Bs[128 * PSTR];

    const int t = threadIdx.x;
    const int lane = t & 63, w = t >> 6;
    const int quad = lane >> 4, l16 = lane & 15;
    const int m0 = blockIdx.y * 128, n0 = blockIdx.x * 128;
    const int wm = (w >> 1) * 64, wn = (w & 1) * 64;
    const int sr = t >> 1, sh = (t & 1) * 16;

    floatx4 acc[4][4];
    #pragma unroll
    for (int mb = 0; mb < 4; ++mb)
        #pragma unroll
        for (int nb = 0; nb < 4; ++nb) acc[mb][nb] = floatx4{0.f, 0.f, 0.f, 0.f};

    for (int k0 = 0; k0 < HIDc; k0 += 32) {
        const _Float16* ap = xh + (size_t)(m0 + sr) * HIDc + k0 + sh;
        const _Float16* bp = Wz + (size_t)(n0 + sr) * HIDc + k0 + sh;
        uint4 a0 = *(const uint4*)(ap);
        uint4 a1 = *(const uint4*)(ap + 8);
        uint4 b0 = *(const uint4*)(bp);
        uint4 b1 = *(const uint4*)(bp + 8);
        __syncthreads();
        *(uint4*)(As + sr * PSTR + sh)     = a0;
        *(uint4*)(As + sr * PSTR + sh + 8) = a1;
        *(uint4*)(Bs + sr * PSTR + sh)     = b0;
        *(uint4*)(Bs + sr * PSTR + sh + 8) = b1;
        __syncthreads();

        half8 af[4], bf[4];
        #pragma unroll
        for (int mb = 0; mb < 4; ++mb)
            af[mb] = *(const half8*)(As + (wm + mb * 16 + l16) * PSTR + quad * 8);
        #pragma unroll
        for (int nb = 0; nb < 4; ++nb)
            bf[nb] = *(const half8*)(Bs + (wn + nb * 16 + l16) * PSTR + quad * 8);
        #pragma unroll
        for (int mb = 0; mb < 4; ++mb)
            #pragma unroll
            for (int nb = 0; nb < 4; ++nb)
                acc[mb][nb] = __builtin_amdgcn_mfma_f32_16x16x32_f16(
                    af[mb], bf[nb], acc[mb][nb], 0, 0, 0);
    }

    #pragma unroll
    for (int nb = 0; nb < 4; ++nb) {
        const int N = n0 + wn + nb * 16 + l16;
        const float bi = bias[N];
        const int h = N >> 6, d = N & 63;
        #pragma unroll
        for (int mb = 0; mb < 4; ++mb) {
            #pragma unroll
            for (int r = 0; r < 4; ++r) {
                const int M = m0 + wm + mb * 16 + quad * 4 + r;
                const int bI = M >> 11, s = M & (Sc - 1);
                const float v = acc[mb][nb][r] + bi;
                if (z == 0)
                    qw[(((size_t)(bI * Hc + h)) * Sc + s) * Dc + d] = (_Float16)(v * 0.125f);
                else if (z == 1)
                    kw[(((size_t)(bI * Hc + h)) * Sc + s) * Dc + d] = (_Float16)v;
                else
                    vt[(((size_t)(bI * Hc + h)) * Dc + d) * Sc + s] = (_Float16)v;
            }
        }
    }
}

// ---------------------------------------------------------------------------
// attn R9: R7/R8 zero-shuffle transposed-scores math, but K/V tiles are
// double-buffered in padded LDS and shared by all 4 waves of the block
// (R8's register prefetch was undone by the compiler — VGPR=84 proved it).
// Per iteration: issue coalesced global loads for tile i+1 -> compute tile i
// from LDS -> write regs to buf[(i+1)&1] -> ONE __syncthreads. The vmcnt
// wait lands after the compute, hiding global latency behind real work
// (m97-verified staging pattern). Stride-72 rows: frag-read banks 2-way max.
// ---------------------------------------------------------------------------
__global__ __launch_bounds__(256, 2) void attn_kernel(
    const _Float16* __restrict__ qw, const _Float16* __restrict__ kw,
    const _Float16* __restrict__ vt, const int* __restrict__ mask,
    float* __restrict__ out)
{
    __shared__ float adder[Sc];                         // 8 KB
    __shared__ __align__(16) _Float16 Ks[2][64][72];    // 18 KB  [key][d]
    __shared__ __align__(16) _Float16 Vs[2][64][72];    // 18 KB  [d][key]

    const int t = threadIdx.x;
    const int lane = t & 63, w = t >> 6;
    const int quad = lane >> 4, l16 = lane & 15;
    const int bh = blockIdx.y;
    const int bI = bh >> 4, h = bh & 15;

    const _Float16* Qp = qw + (size_t)bh * Sc * Dc;
    const _Float16* Kp = kw + (size_t)bh * Sc * Dc;
    const _Float16* Vp = vt + (size_t)bh * Dc * Sc;

    // staging map: 8 threads per 128-B row; two rows per thread (row, row+32)
    const int srow = t >> 3;            // 0..31
    const int scol = (t & 7) * 8;       // elem offset, 16 B per thread

    {   // mask -> additive adder in LDS
        const int4* mp = (const int4*)(mask + bI * Sc);
        #pragma unroll
        for (int i = 0; i < 2; ++i) {
            int4 m4 = mp[t * 2 + i];
            int base = (t * 2 + i) * 4;
            adder[base + 0] = (1.0f - (float)m4.x) * NEG_INF;
            adder[base + 1] = (1.0f - (float)m4.y) * NEG_INF;
            adder[base + 2] = (1.0f - (float)m4.z) * NEG_INF;
            adder[base + 3] = (1.0f - (float)m4.w) * NEG_INF;
        }
    }
    // preload tile 0 into buffer 0 (K tile is 8 KB contiguous; V rows dense)
    #pragma unroll
    for (int hf = 0; hf < 2; ++hf) {
        const int row = srow + 32 * hf;
        uint4 kv = *(const uint4*)(Kp + (size_t)row * Dc + scol);
        uint4 vv = *(const uint4*)(Vp + (size_t)row * Sc + scol);
        *(uint4*)(&Ks[0][row][scol]) = kv;
        *(uint4*)(&Vs[0][row][scol]) = vv;
    }

    const int qrow = blockIdx.x * 128 + w * 32;
    // Q as B-frag for S^T: B[n=q=l16][k=d=quad*8+j]
    half8 aq[2][2];
    #pragma unroll
    for (int s = 0; s < 2; ++s)
        #pragma unroll
        for (int hh = 0; hh < 2; ++hh)
            aq[s][hh] = *(const half8*)(Qp + (size_t)(qrow + 16 * s + l16) * Dc
                                        + hh * 32 + quad * 8);

    floatx4 o[2][4];           // [q-set][d-tile]; D[m=q=quad*4+r][n=d=l16]
    #pragma unroll
    for (int s = 0; s < 2; ++s)
        #pragma unroll
        for (int db = 0; db < 4; ++db) o[s][db] = floatx4{0.f, 0.f, 0.f, 0.f};
    float lsum[2] = {0.f, 0.f};   // per-lane denom partial for q = l16

    __syncthreads();   // adder + tile 0 visible

    #pragma unroll 2
    for (int it = 0; it < Sc / 64; ++it) {
        const int cur = it & 1;
        const int kt = it * 64;
        // ---- issue global loads for tile it+1 (dummy reload of 0 on last)
        const int ktn = (it + 1 < Sc / 64) ? kt + 64 : 0;
        uint4 kstg[2], vstg[2];
        #pragma unroll
        for (int hf = 0; hf < 2; ++hf) {
            const int row = srow + 32 * hf;
            kstg[hf] = *(const uint4*)(Kp + (size_t)(ktn + row) * Dc + scol);
            vstg[hf] = *(const uint4*)(Vp + (size_t)row * Sc + ktn + scol);
        }

        // ---- frags from LDS buf[cur]
        half8 kb[4][2];   // A[m=key=l16][k=d=quad*8+j]
        half4 vb[4][4];   // B[n=d=l16][k=key=quad*4+i]
        #pragma unroll
        for (int nb = 0; nb < 4; ++nb)
            #pragma unroll
            for (int hh = 0; hh < 2; ++hh)
                kb[nb][hh] = *(const half8*)(&Ks[cur][nb * 16 + l16][hh * 32 + quad * 8]);
        #pragma unroll
        for (int nb = 0; nb < 4; ++nb)
            #pragma unroll
            for (int db = 0; db < 4; ++db)
                vb[nb][db] = *(const half4*)(&Vs[cur][db * 16 + l16][nb * 16 + quad * 4]);

        // ---- S^T = K @ Q^T : D[m=key][n=q]
        floatx4 st[2][4];
        #pragma unroll
        for (int s = 0; s < 2; ++s)
            #pragma unroll
            for (int nb = 0; nb < 4; ++nb) {
                floatx4 acc = floatx4{0.f, 0.f, 0.f, 0.f};
                acc = __builtin_amdgcn_mfma_f32_16x16x32_f16(kb[nb][0], aq[s][0], acc, 0, 0, 0);
                acc = __builtin_amdgcn_mfma_f32_16x16x32_f16(kb[nb][1], aq[s][1], acc, 0, 0, 0);
                st[s][nb] = acc;
            }

        // ---- P = exp(S^T + mask): registers are directly the PV A-frags
        half4 pa[2][4];
        #pragma unroll
        for (int nb = 0; nb < 4; ++nb) {
            const float4 a4 = *(const float4*)&adder[kt + nb * 16 + quad * 4];
            const float ad[4] = {a4.x, a4.y, a4.z, a4.w};
            #pragma unroll
            for (int s = 0; s < 2; ++s)
                #pragma unroll
                for (int r = 0; r < 4; ++r) {
                    const float p = __expf(st[s][nb][r] + ad[r]);
                    lsum[s] += p;
                    pa[s][nb][r] = (_Float16)p;
                }
        }

        // ---- O += P @ V (K=16 MFMA)
        #pragma unroll
        for (int s = 0; s < 2; ++s)
            #pragma unroll
            for (int nb = 0; nb < 4; ++nb)
                #pragma unroll
                for (int db = 0; db < 4; ++db)
                    o[s][db] = __builtin_amdgcn_mfma_f32_16x16x16f16(
                        pa[s][nb], vb[nb][db], o[s][db], 0, 0, 0);

        // ---- stage tile it+1 into buf[cur^1] (last read a full iter ago)
        #pragma unroll
        for (int hf = 0; hf < 2; ++hf) {
            const int row = srow + 32 * hf;
            *(uint4*)(&Ks[cur ^ 1][row][scol]) = kstg[hf];
            *(uint4*)(&Vs[cur ^ 1][row][scol]) = vstg[hf];
        }
        __syncthreads();
    }

    // ---- epilogue: reduce denom over quads, redistribute, normalize, store
    #pragma unroll
    for (int s = 0; s < 2; ++s) {
        lsum[s] += __shfl_xor(lsum[s], 16, 64);
        lsum[s] += __shfl_xor(lsum[s], 32, 64);   // total for q=l16, all lanes
    }
    float* op = out + (size_t)bI * Sc * HIDc + h * Dc;
    #pragma unroll
    for (int s = 0; s < 2; ++s)
        #pragma unroll
        for (int r = 0; r < 4; ++r) {
            const float inv = 1.0f / __shfl(lsum[s], quad * 4 + r, 64);
            const int q = qrow + 16 * s + quad * 4 + r;
            #pragma unroll
            for (int db = 0; db < 4; ++db)
                op[(size_t)q * HIDc + db * 16 + l16] = o[s][db][r] * inv;
        }
}

// ---------------------------------------------------------------------------
extern "C" void kernel_launch(void* const* d_in, const int* in_sizes, int n_in,
                              void* d_out, int out_size, void* d_ws, size_t ws_size,
                              hipStream_t stream) {
    const float* x    = (const float*)d_in[0];
    const int*   mask = (const int*)  d_in[1];
    const float* Wq   = (const float*)d_in[2];
    const float* bq   = (const float*)d_in[3];
    const float* Wk   = (const float*)d_in[4];
    const float* bk   = (const float*)d_in[5];
    const float* Wv   = (const float*)d_in[6];
    const float* bv   = (const float*)d_in[7];
    float* out = (float*)d_out;

    // workspace (f16): xh 8MB | Wt 6MB | qw 8MB | kw 8MB | vt 8MB = 38MB
    char* ws = (char*)d_ws;
    _Float16* xh = (_Float16*)(ws);
    _Float16* Wt = (_Float16*)(ws + (size_t)8  * 1024 * 1024);
    _Float16* qw = (_Float16*)(ws + (size_t)14 * 1024 * 1024);
    _Float16* kw = (_Float16*)(ws + (size_t)22 * 1024 * 1024);
    _Float16* vt = (_Float16*)(ws + (size_t)30 * 1024 * 1024);

    cvt_x_kernel<<<(Bc * Sc * HIDc) / (256 * 8), 256, 0, stream>>>(x, xh);
    cvt_w_kernel<<<dim3(HIDc / 64, HIDc / 64, 3), 256, 0, stream>>>(Wq, Wk, Wv, Wt);
    proj_kernel<<<dim3(HIDc / 128, (Bc * Sc) / 128, 3), 256, 0, stream>>>(
        xh, Wt, bq, bk, bv, qw, kw, vt);
    attn_kernel<<<dim3(Sc / 128, Bc * Hc), 256, 0, stream>>>(qw, kw, vt, mask, out);
}

// Round 10
// 188.493 us; speedup vs baseline: 1.7209x; 1.0676x over previous
//
#include <hip/hip_runtime.h>
#include <cstddef>

constexpr int Bc = 2, Sc = 2048, Hc = 16, Dc = 64, HIDc = 1024;
#define NEG_INF -10000.0f

typedef _Float16 half8  __attribute__((ext_vector_type(8)));  // K=32 MFMA A/B frag
typedef _Float16 half4  __attribute__((ext_vector_type(4)));  // K=16 MFMA A/B frag
typedef float   floatx4 __attribute__((ext_vector_type(4)));  // MFMA C/D frag

// ---------------------------------------------------------------------------
// cvt_x: x fp32 [4096][1024] -> f16 same layout. 8 elements/thread.
// ---------------------------------------------------------------------------
__global__ __launch_bounds__(256) void cvt_x_kernel(const float* __restrict__ x,
                                                    _Float16* __restrict__ xh) {
    int i = (blockIdx.x * 256 + threadIdx.x) * 8;
    float4 a = *(const float4*)(x + i);
    float4 b = *(const float4*)(x + i + 4);
    half8 h;
    h[0] = (_Float16)a.x; h[1] = (_Float16)a.y; h[2] = (_Float16)a.z; h[3] = (_Float16)a.w;
    h[4] = (_Float16)b.x; h[5] = (_Float16)b.y; h[6] = (_Float16)b.z; h[7] = (_Float16)b.w;
    *(half8*)(xh + i) = h;
}

// ---------------------------------------------------------------------------
// cvt_w: W fp32 [k][n] -> Wt f16 [n][k] (transposed), per z in {q,k,v}.
// ---------------------------------------------------------------------------
__global__ __launch_bounds__(256) void cvt_w_kernel(const float* __restrict__ Wq,
                                                    const float* __restrict__ Wk,
                                                    const float* __restrict__ Wv,
                                                    _Float16* __restrict__ Wt) {
    const float* W = (blockIdx.z == 0) ? Wq : (blockIdx.z == 1) ? Wk : Wv;
    _Float16* out = Wt + (size_t)blockIdx.z * HIDc * HIDc;
    __shared__ _Float16 T[64][65];
    const int t = threadIdx.x;
    const int kb = blockIdx.x * 64, nb = blockIdx.y * 64;
    const int r = t >> 2, c4 = (t & 3) * 16;
    #pragma unroll
    for (int i = 0; i < 16; i += 4) {
        float4 a = *(const float4*)(W + (size_t)(kb + r) * HIDc + nb + c4 + i);
        T[c4 + i + 0][r] = (_Float16)a.x;
        T[c4 + i + 1][r] = (_Float16)a.y;
        T[c4 + i + 2][r] = (_Float16)a.z;
        T[c4 + i + 3][r] = (_Float16)a.w;
    }
    __syncthreads();
    const int n = t >> 2, k4 = (t & 3) * 16;
    half8 o0, o1;
    #pragma unroll
    for (int j = 0; j < 8; ++j) { o0[j] = T[n][k4 + j]; o1[j] = T[n][k4 + 8 + j]; }
    *(half8*)(out + (size_t)(nb + n) * HIDc + kb + k4)     = o0;
    *(half8*)(out + (size_t)(nb + n) * HIDc + kb + k4 + 8) = o1;
}

// ---------------------------------------------------------------------------
// proj R10: same math/layout as R5-R9 (passing), but K-loop restructured to
// the R9-attn single-barrier LDS double-buffer pipeline: issue next tile's
// global loads -> compute current tile from buf[cur] -> write staged regs to
// buf[cur^1] -> ONE __syncthreads. The vmcnt wait lands after the MFMAs
// instead of at a barrier before them (the old 2-barrier loop exposed ~600
// cycles of global latency on every one of the 32 K-iterations).
// ---------------------------------------------------------------------------
#define PSTR 40
__global__ __launch_bounds__(256, 2) void proj_kernel(
    const _Float16* __restrict__ xh, const _Float16* __restrict__ Wt,
    const float* __restrict__ bq, const float* __restrict__ bk, const float* __restrict__ bv,
    _Float16* __restrict__ qw, _Float16* __restrict__ kw, _Float16* __restrict__ vt)
{
    const int z = blockIdx.z;
    const _Float16* Wz = Wt + (size_t)z * HIDc * HIDc;
    const float* bias = (z == 0) ? bq : (z == 1) ? bk : bv;

    __shared__ _Float16 As[2][128 * PSTR];   // 10 KB x 2
    __shared__ _Float16 Bs[2][128 * PSTR];   // 10 KB x 2

    const int t = threadIdx.x;
    const int lane = t & 63, w = t >> 6;
    const int quad = lane >> 4, l16 = lane & 15;
    const int m0 = blockIdx.y * 128, n0 = blockIdx.x * 128;
    const int wm = (w >> 1) * 64, wn = (w & 1) * 64;
    const int sr = t >> 1, sh = (t & 1) * 16;

    floatx4 acc[4][4];
    #pragma unroll
    for (int mb = 0; mb < 4; ++mb)
        #pragma unroll
        for (int nb = 0; nb < 4; ++nb) acc[mb][nb] = floatx4{0.f, 0.f, 0.f, 0.f};

    // ---- preload k-tile 0 into buffer 0
    {
        const _Float16* ap = xh + (size_t)(m0 + sr) * HIDc + sh;
        const _Float16* bp = Wz + (size_t)(n0 + sr) * HIDc + sh;
        *(uint4*)(As[0] + sr * PSTR + sh)     = *(const uint4*)(ap);
        *(uint4*)(As[0] + sr * PSTR + sh + 8) = *(const uint4*)(ap + 8);
        *(uint4*)(Bs[0] + sr * PSTR + sh)     = *(const uint4*)(bp);
        *(uint4*)(Bs[0] + sr * PSTR + sh + 8) = *(const uint4*)(bp + 8);
    }
    __syncthreads();

    #pragma unroll 2
    for (int it = 0; it < HIDc / 32; ++it) {
        const int cur = it & 1;
        // ---- issue global loads for tile it+1 (dummy reload of 0 on last)
        const int kn = (it + 1 < HIDc / 32) ? (it + 1) * 32 : 0;
        const _Float16* ap = xh + (size_t)(m0 + sr) * HIDc + kn + sh;
        const _Float16* bp = Wz + (size_t)(n0 + sr) * HIDc + kn + sh;
        uint4 a0 = *(const uint4*)(ap);
        uint4 a1 = *(const uint4*)(ap + 8);
        uint4 b0 = *(const uint4*)(bp);
        uint4 b1 = *(const uint4*)(bp + 8);

        // ---- frags from buf[cur] + MFMA
        half8 af[4], bf[4];
        #pragma unroll
        for (int mb = 0; mb < 4; ++mb)
            af[mb] = *(const half8*)(As[cur] + (wm + mb * 16 + l16) * PSTR + quad * 8);
        #pragma unroll
        for (int nb = 0; nb < 4; ++nb)
            bf[nb] = *(const half8*)(Bs[cur] + (wn + nb * 16 + l16) * PSTR + quad * 8);
        #pragma unroll
        for (int mb = 0; mb < 4; ++mb)
            #pragma unroll
            for (int nb = 0; nb < 4; ++nb)
                acc[mb][nb] = __builtin_amdgcn_mfma_f32_16x16x32_f16(
                    af[mb], bf[nb], acc[mb][nb], 0, 0, 0);

        // ---- stage tile it+1 into buf[cur^1] (readers finished last iter)
        *(uint4*)(As[cur ^ 1] + sr * PSTR + sh)     = a0;
        *(uint4*)(As[cur ^ 1] + sr * PSTR + sh + 8) = a1;
        *(uint4*)(Bs[cur ^ 1] + sr * PSTR + sh)     = b0;
        *(uint4*)(Bs[cur ^ 1] + sr * PSTR + sh + 8) = b1;
        __syncthreads();
    }

    // epilogue: C/D mapping col=lane&15, row=quad*4+reg (m89/m91-verified)
    #pragma unroll
    for (int nb = 0; nb < 4; ++nb) {
        const int N = n0 + wn + nb * 16 + l16;
        const float bi = bias[N];
        const int h = N >> 6, d = N & 63;
        #pragma unroll
        for (int mb = 0; mb < 4; ++mb) {
            #pragma unroll
            for (int r = 0; r < 4; ++r) {
                const int M = m0 + wm + mb * 16 + quad * 4 + r;
                const int bI = M >> 11, s = M & (Sc - 1);
                const float v = acc[mb][nb][r] + bi;
                if (z == 0)
                    qw[(((size_t)(bI * Hc + h)) * Sc + s) * Dc + d] = (_Float16)(v * 0.125f);
                else if (z == 1)
                    kw[(((size_t)(bI * Hc + h)) * Sc + s) * Dc + d] = (_Float16)v;
                else
                    vt[(((size_t)(bI * Hc + h)) * Dc + d) * Sc + s] = (_Float16)v;
            }
        }
    }
}

// ---------------------------------------------------------------------------
// attn: byte-identical to R9 (passing, < 72 us). Zero-shuffle transposed-
// scores math; K/V tiles double-buffered in padded LDS, shared by 4 waves;
// one barrier per key-tile.
// ---------------------------------------------------------------------------
__global__ __launch_bounds__(256, 2) void attn_kernel(
    const _Float16* __restrict__ qw, const _Float16* __restrict__ kw,
    const _Float16* __restrict__ vt, const int* __restrict__ mask,
    float* __restrict__ out)
{
    __shared__ float adder[Sc];                         // 8 KB
    __shared__ __align__(16) _Float16 Ks[2][64][72];    // 18 KB  [key][d]
    __shared__ __align__(16) _Float16 Vs[2][64][72];    // 18 KB  [d][key]

    const int t = threadIdx.x;
    const int lane = t & 63, w = t >> 6;
    const int quad = lane >> 4, l16 = lane & 15;
    const int bh = blockIdx.y;
    const int bI = bh >> 4, h = bh & 15;

    const _Float16* Qp = qw + (size_t)bh * Sc * Dc;
    const _Float16* Kp = kw + (size_t)bh * Sc * Dc;
    const _Float16* Vp = vt + (size_t)bh * Dc * Sc;

    const int srow = t >> 3;            // 0..31
    const int scol = (t & 7) * 8;       // elem offset, 16 B per thread

    {   // mask -> additive adder in LDS
        const int4* mp = (const int4*)(mask + bI * Sc);
        #pragma unroll
        for (int i = 0; i < 2; ++i) {
            int4 m4 = mp[t * 2 + i];
            int base = (t * 2 + i) * 4;
            adder[base + 0] = (1.0f - (float)m4.x) * NEG_INF;
            adder[base + 1] = (1.0f - (float)m4.y) * NEG_INF;
            adder[base + 2] = (1.0f - (float)m4.z) * NEG_INF;
            adder[base + 3] = (1.0f - (float)m4.w) * NEG_INF;
        }
    }
    // preload tile 0 into buffer 0
    #pragma unroll
    for (int hf = 0; hf < 2; ++hf) {
        const int row = srow + 32 * hf;
        uint4 kv = *(const uint4*)(Kp + (size_t)row * Dc + scol);
        uint4 vv = *(const uint4*)(Vp + (size_t)row * Sc + scol);
        *(uint4*)(&Ks[0][row][scol]) = kv;
        *(uint4*)(&Vs[0][row][scol]) = vv;
    }

    const int qrow = blockIdx.x * 128 + w * 32;
    half8 aq[2][2];
    #pragma unroll
    for (int s = 0; s < 2; ++s)
        #pragma unroll
        for (int hh = 0; hh < 2; ++hh)
            aq[s][hh] = *(const half8*)(Qp + (size_t)(qrow + 16 * s + l16) * Dc
                                        + hh * 32 + quad * 8);

    floatx4 o[2][4];
    #pragma unroll
    for (int s = 0; s < 2; ++s)
        #pragma unroll
        for (int db = 0; db < 4; ++db) o[s][db] = floatx4{0.f, 0.f, 0.f, 0.f};
    float lsum[2] = {0.f, 0.f};

    __syncthreads();   // adder + tile 0 visible

    #pragma unroll 2
    for (int it = 0; it < Sc / 64; ++it) {
        const int cur = it & 1;
        const int kt = it * 64;
        const int ktn = (it + 1 < Sc / 64) ? kt + 64 : 0;
        uint4 kstg[2], vstg[2];
        #pragma unroll
        for (int hf = 0; hf < 2; ++hf) {
            const int row = srow + 32 * hf;
            kstg[hf] = *(const uint4*)(Kp + (size_t)(ktn + row) * Dc + scol);
            vstg[hf] = *(const uint4*)(Vp + (size_t)row * Sc + ktn + scol);
        }

        half8 kb[4][2];   // A[m=key=l16][k=d=quad*8+j]
        half4 vb[4][4];   // B[n=d=l16][k=key=quad*4+i]
        #pragma unroll
        for (int nb = 0; nb < 4; ++nb)
            #pragma unroll
            for (int hh = 0; hh < 2; ++hh)
                kb[nb][hh] = *(const half8*)(&Ks[cur][nb * 16 + l16][hh * 32 + quad * 8]);
        #pragma unroll
        for (int nb = 0; nb < 4; ++nb)
            #pragma unroll
            for (int db = 0; db < 4; ++db)
                vb[nb][db] = *(const half4*)(&Vs[cur][db * 16 + l16][nb * 16 + quad * 4]);

        floatx4 st[2][4];
        #pragma unroll
        for (int s = 0; s < 2; ++s)
            #pragma unroll
            for (int nb = 0; nb < 4; ++nb) {
                floatx4 acc = floatx4{0.f, 0.f, 0.f, 0.f};
                acc = __builtin_amdgcn_mfma_f32_16x16x32_f16(kb[nb][0], aq[s][0], acc, 0, 0, 0);
                acc = __builtin_amdgcn_mfma_f32_16x16x32_f16(kb[nb][1], aq[s][1], acc, 0, 0, 0);
                st[s][nb] = acc;
            }

        half4 pa[2][4];
        #pragma unroll
        for (int nb = 0; nb < 4; ++nb) {
            const float4 a4 = *(const float4*)&adder[kt + nb * 16 + quad * 4];
            const float ad[4] = {a4.x, a4.y, a4.z, a4.w};
            #pragma unroll
            for (int s = 0; s < 2; ++s)
                #pragma unroll
                for (int r = 0; r < 4; ++r) {
                    const float p = __expf(st[s][nb][r] + ad[r]);
                    lsum[s] += p;
                    pa[s][nb][r] = (_Float16)p;
                }
        }

        #pragma unroll
        for (int s = 0; s < 2; ++s)
            #pragma unroll
            for (int nb = 0; nb < 4; ++nb)
                #pragma unroll
                for (int db = 0; db < 4; ++db)
                    o[s][db] = __builtin_amdgcn_mfma_f32_16x16x16f16(
                        pa[s][nb], vb[nb][db], o[s][db], 0, 0, 0);

        #pragma unroll
        for (int hf = 0; hf < 2; ++hf) {
            const int row = srow + 32 * hf;
            *(uint4*)(&Ks[cur ^ 1][row][scol]) = kstg[hf];
            *(uint4*)(&Vs[cur ^ 1][row][scol]) = vstg[hf];
        }
        __syncthreads();
    }

    #pragma unroll
    for (int s = 0; s < 2; ++s) {
        lsum[s] += __shfl_xor(lsum[s], 16, 64);
        lsum[s] += __shfl_xor(lsum[s], 32, 64);
    }
    float* op = out + (size_t)bI * Sc * HIDc + h * Dc;
    #pragma unroll
    for (int s = 0; s < 2; ++s)
        #pragma unroll
        for (int r = 0; r < 4; ++r) {
            const float inv = 1.0f / __shfl(lsum[s], quad * 4 + r, 64);
            const int q = qrow + 16 * s + quad * 4 + r;
            #pragma unroll
            for (int db = 0; db < 4; ++db)
                op[(size_t)q * HIDc + db * 16 + l16] = o[s][db][r] * inv;
        }
}

// ---------------------------------------------------------------------------
extern "C" void kernel_launch(void* const* d_in, const int* in_sizes, int n_in,
                              void* d_out, int out_size, void* d_ws, size_t ws_size,
                              hipStream_t stream) {
    const float* x    = (const float*)d_in[0];
    const int*   mask = (const int*)  d_in[1];
    const float* Wq   = (const float*)d_in[2];
    const float* bq   = (const float*)d_in[3];
    const float* Wk   = (const float*)d_in[4];
    const float* bk   = (const float*)d_in[5];
    const float* Wv   = (const float*)d_in[6];
    const float* bv   = (const float*)d_in[7];
    float* out = (float*)d_out;

    // workspace (f16): xh 8MB | Wt 6MB | qw 8MB | kw 8MB | vt 8MB = 38MB
    char* ws = (char*)d_ws;
    _Float16* xh = (_Float16*)(ws);
    _Float16* Wt = (_Float16*)(ws + (size_t)8  * 1024 * 1024);
    _Float16* qw = (_Float16*)(ws + (size_t)14 * 1024 * 1024);
    _Float16* kw = (_Float16*)(ws + (size_t)22 * 1024 * 1024);
    _Float16* vt = (_Float16*)(ws + (size_t)30 * 1024 * 1024);

    cvt_x_kernel<<<(Bc * Sc * HIDc) / (256 * 8), 256, 0, stream>>>(x, xh);
    cvt_w_kernel<<<dim3(HIDc / 64, HIDc / 64, 3), 256, 0, stream>>>(Wq, Wk, Wv, Wt);
    proj_kernel<<<dim3(HIDc / 128, (Bc * Sc) / 128, 3), 256, 0, stream>>>(
        xh, Wt, bq, bk, bv, qw, kw, vt);
    attn_kernel<<<dim3(Sc / 128, Bc * Hc), 256, 0, stream>>>(qw, kw, vt, mask, out);
}